// Round 11
// baseline (663.530 us; speedup 1.0000x reference)
//
#include <hip/hip_runtime.h>
#include <math.h>
#include <float.h>

#define N_NODES 20000
#define N_PAD 20032          // 313*64
#define N_EDGES 320000
#define NGRAPH 64
#define NLAYER 3
#define BN_EPS 1e-5f

typedef short bf16x8 __attribute__((ext_vector_type(8)));
typedef float f32x4 __attribute__((ext_vector_type(4)));

__device__ inline unsigned short f2bf(float f) {
    unsigned int u = __float_as_uint(f);
    unsigned int r = u + 0x7FFF + ((u >> 16) & 1);   // RNE
    return (unsigned short)(r >> 16);
}
__device__ inline float bf2f(unsigned short s) {
    return __uint_as_float((unsigned int)s << 16);
}

// ---------------- CSR construction ----------------
__global__ void count_kernel(const int* __restrict__ ei, int* __restrict__ cnt) {
    int e = blockIdx.x * blockDim.x + threadIdx.x;
    if (e < N_EDGES) atomicAdd(&cnt[ei[N_EDGES + e]], 1);
}

__global__ void scan_kernel(const int* __restrict__ cnt, int* __restrict__ rowptr) {
    __shared__ int sh[256];
    int t = threadIdx.x;
    const int CH = (N_NODES + 255) / 256;
    int base = t * CH;
    int s = 0;
    for (int i = 0; i < CH; i++) { int idx = base + i; if (idx < N_NODES) s += cnt[idx]; }
    sh[t] = s;
    __syncthreads();
    for (int off = 1; off < 256; off <<= 1) {
        int v = sh[t];
        int add = (t >= off) ? sh[t - off] : 0;
        __syncthreads();
        sh[t] = v + add;
        __syncthreads();
    }
    int run = sh[t] - s;
    for (int i = 0; i < CH; i++) {
        int idx = base + i;
        if (idx < N_NODES) { rowptr[idx] = run; run += cnt[idx]; }
    }
    if (t == 255) rowptr[N_NODES] = sh[255];
}

__global__ void fill_kernel(const int* __restrict__ ei, const int* __restrict__ rowptr,
                            int* __restrict__ cur, int* __restrict__ eidx,
                            int* __restrict__ esrc) {
    int e = blockIdx.x * blockDim.x + threadIdx.x;
    if (e < N_EDGES) {
        int dst = ei[N_EDGES + e];
        int pos = atomicAdd(&cur[dst], 1);
        int slot = rowptr[dst] + pos;
        eidx[slot] = e;
        esrc[slot] = ei[e];
    }
}

// permute edge_attr into CSR order, converting to bf16
__global__ void permute_ea_b_kernel(const float* __restrict__ edge_attr,
                                    const int* __restrict__ eidx,
                                    unsigned short* __restrict__ eaPb) {
    int idx = blockIdx.x * blockDim.x + threadIdx.x;   // quad index
    if (idx < N_EDGES * 16) {
        int j = idx >> 4, c4 = idx & 15;
        float4 v = *(const float4*)(edge_attr + (size_t)eidx[j] * 64 + c4 * 4);
        ((ushort4*)eaPb)[idx] = make_ushort4(f2bf(v.x), f2bf(v.y), f2bf(v.z), f2bf(v.w));
    }
}

// ---------------- prep: weight panel build + x->bf16, one kernel (64-thr blocks) -----
// blocks [0, 1280*NLAYER): wallt work. blocks [1280*NLAYER, +5008): xtobf work.
__global__ void prep_kernel(const float* __restrict__ Wq, const float* __restrict__ Wk,
                            const float* __restrict__ Wv, const float* __restrict__ Ws,
                            const float* __restrict__ We,
                            const float* __restrict__ bq, const float* __restrict__ bk,
                            const float* __restrict__ bv, const float* __restrict__ bs,
                            const float* __restrict__ x,
                            unsigned short* __restrict__ WallT, float* __restrict__ ball,
                            unsigned short* __restrict__ xbf) {
    int bid = blockIdx.x, k = threadIdx.x;
    if (bid < 1280 * NLAYER) {
        int l = bid / 1280, c = bid % 1280;
        int seg = c >> 8, ci = c & 255;
        if (seg < 4) {
            const float* W; const float* b;
            switch (seg) {
                case 0:  W = Wq; b = bq; break;
                case 1:  W = Wk; b = bk; break;
                case 2:  W = Wv; b = bv; break;
                default: W = Ws; b = bs; break;
            }
            WallT[(size_t)l * 81920 + c * 64 + k] = f2bf(W[l * 16384 + k * 256 + ci]);
            if (k == 0) ball[l * 1280 + c] = b[l * 256 + ci];
        } else {
            int h = ci >> 6, d = ci & 63;
            const float* Wql = Wq + l * 16384;
            const float* Wel = We + l * 16384;
            float acc = 0.f;
            for (int cc = 0; cc < 64; cc++)
                acc += Wql[k * 256 + h * 64 + cc] * Wel[d * 256 + h * 64 + cc];
            WallT[(size_t)l * 81920 + c * 64 + k] = f2bf(acc);
            if (k == 0) {
                const float* bql = bq + l * 256;
                float ab = 0.f;
                for (int cc = 0; cc < 64; cc++)
                    ab += bql[h * 64 + cc] * Wel[d * 256 + h * 64 + cc];
                ball[l * 1280 + c] = ab;
            }
        }
    } else {
        int i4 = (bid - 1280 * NLAYER) * 64 + k;
        if (i4 < N_PAD * 16) {
            int n = i4 >> 4;
            ushort4 o;
            if (n < N_NODES) {
                float4 v = ((const float4*)x)[i4];
                o = make_ushort4(f2bf(v.x), f2bf(v.y), f2bf(v.z), f2bf(v.w));
            } else o = make_ushort4(0, 0, 0, 0);
            ((ushort4*)xbf)[i4] = o;
        }
    }
}

// ---------------- fused 5-way node linear via MFMA; k/v packed fp8 -------------------
__global__ __launch_bounds__(256) void gemm_qkvsu4_kernel(
    const unsigned short* __restrict__ xbf,     // [N_PAD][64]
    const unsigned short* __restrict__ WallT,   // [1280][64] layer slice
    const float* __restrict__ ball,             // [1280]
    unsigned short* __restrict__ qbf, unsigned char* __restrict__ kvf8,
    unsigned short* __restrict__ sbf, unsigned short* __restrict__ ubf) {
    int t = threadIdx.x, wid = t >> 6, lane = t & 63;
    int lrow = lane & 15, lk = lane >> 4;

    bf16x8 bfrag[2][4][2];
    float bias[2][4];
    int kind[2];                 // 0 = bf16 out, 1 = fp8 k, 2 = fp8 v
    unsigned short* outb[2]; int obase[2];
#pragma unroll
    for (int cg = 0; cg < 2; cg++) {
        int ys = blockIdx.y * 2 + cg;
        int col0 = ys * 64;
        int q = ys & 3;
        if (ys < 4)       { kind[cg] = 0; outb[cg] = qbf; obase[cg] = q * 64; }
        else if (ys < 8)  { kind[cg] = 1; outb[cg] = nullptr; obase[cg] = q * 64; }
        else if (ys < 12) { kind[cg] = 2; outb[cg] = nullptr; obase[cg] = q * 64; }
        else if (ys < 16) { kind[cg] = 0; outb[cg] = sbf; obase[cg] = q * 64; }
        else              { kind[cg] = 0; outb[cg] = ubf; obase[cg] = q * 64; }
#pragma unroll
        for (int ct = 0; ct < 4; ct++) {
#pragma unroll
            for (int kc = 0; kc < 2; kc++)
                bfrag[cg][ct][kc] = *(const bf16x8*)(WallT +
                    (size_t)(col0 + ct * 16 + lrow) * 64 + kc * 32 + lk * 8);
            bias[cg][ct] = ball[col0 + ct * 16 + lrow];
        }
    }

    for (int nc = blockIdx.x; nc < N_PAD / 64; nc += gridDim.x) {
        int n0 = nc * 64 + wid * 16;
        bf16x8 a0 = *(const bf16x8*)(xbf + (size_t)(n0 + lrow) * 64 + lk * 8);
        bf16x8 a1 = *(const bf16x8*)(xbf + (size_t)(n0 + lrow) * 64 + 32 + lk * 8);
#pragma unroll
        for (int cg = 0; cg < 2; cg++) {
#pragma unroll
            for (int ct = 0; ct < 4; ct++) {
                f32x4 acc = {bias[cg][ct], bias[cg][ct], bias[cg][ct], bias[cg][ct]};
                acc = __builtin_amdgcn_mfma_f32_16x16x32_bf16(a0, bfrag[cg][ct][0], acc, 0, 0, 0);
                acc = __builtin_amdgcn_mfma_f32_16x16x32_bf16(a1, bfrag[cg][ct][1], acc, 0, 0, 0);
                int cl = ct * 16 + lrow;
#pragma unroll
                for (int r = 0; r < 4; r++) {
                    int n = n0 + lk * 4 + r;
                    if (n < N_NODES) {
                        if (kind[cg] == 0) {
                            outb[cg][(size_t)n * 256 + obase[cg] + cl] = f2bf(acc[r]);
                        } else {
                            unsigned int pk = __builtin_amdgcn_cvt_pk_fp8_f32(
                                acc[r], acc[r], 0, false);
                            int ch = obase[cg] + cl;
                            kvf8[(size_t)n * 512 + 2 * ch + (kind[cg] - 1)] =
                                (unsigned char)pk;
                        }
                    }
                }
            }
        }
    }
}

// ---------------- fully fused attention: edge loop + msg GEMV + BN stats -------------
// phase 1: wave w handles node base+w (edge loop, fp8 kv gather, readlane addressing);
//          stores (acc*inv + skip) and racc*inv to LDS.
// phase 2: thread t handles channel t for all 4 nodes: msg = racc @ We, write hbf,
//          accumulate BN partials (scalar per thread). 2 atomics per thread at end.
__global__ __launch_bounds__(256) void attn12_kernel(
    const unsigned short* __restrict__ eaPb,  // bf16 CSR-ordered, or NULL
    const float* __restrict__ ea_f32,         // fallback: original fp32
    const int* __restrict__ eaidx,            // fallback index
    const int* __restrict__ rowptr, const int* __restrict__ esrc,
    const unsigned short* __restrict__ qbf, const unsigned short* __restrict__ ubf,
    const unsigned char* __restrict__ kvf8,   // [n][512]B: byte 2c=k[c], 2c+1=v[c]
    const unsigned short* __restrict__ sbf,
    const float* __restrict__ We,             // [64][256] fp32 layer slice
    unsigned short* __restrict__ hbf,         // out: bf16 h (pre-BN)
    float* __restrict__ statsL) {             // [8][512] BN partials
    __shared__ unsigned short WeLT[256][68];  // transposed, padded: WeLT[c][d]
    __shared__ float accL[4][256];
    __shared__ float raccL[4][256];
    int t = threadIdx.x;
    int wid = t >> 6, lane = t & 63;
    int c4 = lane * 4;
    int ec4 = (lane & 15) * 4;

    // stage We^T (bf16) into LDS
    for (int i = t; i < 16384; i += 256) {
        int c = i & 255, d = i >> 8;
        WeLT[c][d] = f2bf(We[d * 256 + c]);
    }
    __syncthreads();

    float bns = 0.f, bns2 = 0.f;
    int h64 = t & 192;

    for (int base = blockIdx.x * 4; base < N_NODES; base += gridDim.x * 4) {
        // ---- phase 1: per-wave edge loop ----
        int n = base + wid;
        ushort4 qu = *(const ushort4*)(qbf + (size_t)n * 256 + c4);
        ushort4 uu = *(const ushort4*)(ubf + (size_t)n * 256 + c4);
        float4 q4 = make_float4(bf2f(qu.x), bf2f(qu.y), bf2f(qu.z), bf2f(qu.w));
        float4 u4 = make_float4(bf2f(uu.x), bf2f(uu.y), bf2f(uu.z), bf2f(uu.w));
        int j0 = rowptr[n];
        int cnt = rowptr[n + 1] - j0;
        float l = 0.f;
        float4 a4 = make_float4(0.f, 0.f, 0.f, 0.f), r4 = a4;

        for (int eb = 0; eb < cnt; eb += 64) {
            int nb = cnt - eb;
            if (nb > 64) nb = 64;
            int jb = j0 + eb;
            int srcv = (lane < nb) ? esrc[jb + lane] : 0;
            uint2 kvA = make_uint2(0, 0), kvB = kvA;
            float4 eA = make_float4(0.f, 0.f, 0.f, 0.f), eB = eA;

#define LOADE(KV, EV, JJ) do { \
        int _s = __builtin_amdgcn_readlane(srcv, (JJ)); \
        KV = *(const uint2*)(kvf8 + (size_t)_s * 512 + c4 * 2); \
        int _j = jb + (JJ); \
        if (eaPb) { ushort4 _e = *(const ushort4*)(eaPb + (size_t)_j * 64 + ec4); \
                    EV = make_float4(bf2f(_e.x), bf2f(_e.y), bf2f(_e.z), bf2f(_e.w)); } \
        else { EV = *(const float4*)(ea_f32 + (size_t)eaidx[_j] * 64 + ec4); } \
    } while (0)

#define PROC(KV, EV) do { \
        float K0 = __builtin_amdgcn_cvt_f32_fp8(KV.x, 0); \
        float V0 = __builtin_amdgcn_cvt_f32_fp8(KV.x, 1); \
        float K1 = __builtin_amdgcn_cvt_f32_fp8(KV.x, 2); \
        float V1 = __builtin_amdgcn_cvt_f32_fp8(KV.x, 3); \
        float K2 = __builtin_amdgcn_cvt_f32_fp8(KV.y, 0); \
        float V2 = __builtin_amdgcn_cvt_f32_fp8(KV.y, 1); \
        float K3 = __builtin_amdgcn_cvt_f32_fp8(KV.y, 2); \
        float V3 = __builtin_amdgcn_cvt_f32_fp8(KV.y, 3); \
        float p = q4.x * K0 + q4.y * K1 + q4.z * K2 + q4.w * K3 \
                + u4.x * EV.x + u4.y * EV.y + u4.z * EV.z + u4.w * EV.w; \
        p += __shfl_xor(p, 1); p += __shfl_xor(p, 2); \
        p += __shfl_xor(p, 4); p += __shfl_xor(p, 8); \
        p = __expf(p * 0.125f); \
        l += p; \
        a4.x += p * V0; a4.y += p * V1; a4.z += p * V2; a4.w += p * V3; \
        r4.x += p * EV.x; r4.y += p * EV.y; r4.z += p * EV.z; r4.w += p * EV.w; \
    } while (0)

            if (nb > 0) LOADE(kvA, eA, 0);
            if (nb > 1) LOADE(kvB, eB, 1);
            int jj = 0;
            for (; jj + 1 < nb; jj += 2) {
                uint2 kv0 = kvA; float4 e0 = eA;
                if (jj + 2 < nb) LOADE(kvA, eA, jj + 2);
                PROC(kv0, e0);
                uint2 kv1 = kvB; float4 e1 = eB;
                if (jj + 3 < nb) LOADE(kvB, eB, jj + 3);
                PROC(kv1, e1);
            }
            if (jj < nb) PROC(kvA, eA);
#undef LOADE
#undef PROC
        }
        float inv = (l > 0.f) ? 1.f / l : 0.f;
        ushort4 su = *(const ushort4*)(sbf + (size_t)n * 256 + c4);
        accL[wid][c4 + 0] = a4.x * inv + bf2f(su.x);
        accL[wid][c4 + 1] = a4.y * inv + bf2f(su.y);
        accL[wid][c4 + 2] = a4.z * inv + bf2f(su.z);
        accL[wid][c4 + 3] = a4.w * inv + bf2f(su.w);
        *(float4*)(raccL[wid] + c4) = make_float4(r4.x * inv, r4.y * inv,
                                                  r4.z * inv, r4.w * inv);
        __syncthreads();

        // ---- phase 2: per-thread channel t, all 4 nodes ----
#pragma unroll
        for (int ni = 0; ni < 4; ni++) {
            float msg = 0.f;
#pragma unroll
            for (int d4 = 0; d4 < 16; d4++) {
                float4 rv = *(const float4*)(raccL[ni] + h64 + d4 * 4);
                ushort4 wv = *(const ushort4*)(&WeLT[t][d4 * 4]);
                msg += rv.x * bf2f(wv.x) + rv.y * bf2f(wv.y)
                     + rv.z * bf2f(wv.z) + rv.w * bf2f(wv.w);
            }
            float hv = accL[ni][t] + msg;
            hbf[(size_t)(base + ni) * 256 + t] = f2bf(hv);
            bns += hv; bns2 += hv * hv;
        }
        __syncthreads();
    }
    int sbase = (blockIdx.x & 7) * 512;
    atomicAdd(&statsL[sbase + t], bns);
    atomicAdd(&statsL[sbase + 256 + t], bns2);
}

// ---------------- x = relu(BN(h) @ Wt + bt): BN-fold computed in-block, MFMA, pooling -
__global__ __launch_bounds__(256) void xform5_kernel(
    const unsigned short* __restrict__ hbf,     // [N_PAD][256]
    const float* __restrict__ Wt,               // [256][64] raw fp32 layer slice
    const float* __restrict__ gamma, const float* __restrict__ beta,
    const float* __restrict__ bt,
    const float* __restrict__ statsL,           // [8][512]
    unsigned short* __restrict__ xbf,           // [N_PAD][64]
    float* __restrict__ poolmx, float* __restrict__ poolsm, int layer) {
    __shared__ float xt[64][65];
    __shared__ float red[4][2][2][64];
    __shared__ float aL[256], bbL[256], partb[256], biasL[64];
    int t = threadIdx.x, wid = t >> 6, lane = t & 63;
    int lrow = lane & 15, lk = lane >> 4;

    // ---- BN fold (redundant per block; cheap) ----
    {
        float sum = 0.f, sq = 0.f;
#pragma unroll
        for (int s = 0; s < 8; s++) {
            sum += statsL[s * 512 + t];
            sq  += statsL[s * 512 + 256 + t];
        }
        float mean = sum * (1.f / N_NODES);
        float var = sq * (1.f / N_NODES) - mean * mean;
        float a = rsqrtf(var + BN_EPS) * gamma[t];
        aL[t] = a;
        bbL[t] = beta[t] - mean * a;
    }
    __syncthreads();
    {
        float p = 0.f;
        int o = t & 63, kq = (t >> 6) * 64;
        for (int kk = kq; kk < kq + 64; kk++) p += bbL[kk] * Wt[kk * 64 + o];
        partb[t] = p;
    }
    __syncthreads();
    if (t < 64) biasL[t] = bt[t] + partb[t] + partb[64 + t] + partb[128 + t] + partb[192 + t];
    __syncthreads();

    // ---- folded bf16 B fragments ----
    bf16x8 bfrag[4][8];
#pragma unroll
    for (int ct = 0; ct < 4; ct++) {
        int o = ct * 16 + lrow;
#pragma unroll
        for (int kc = 0; kc < 8; kc++) {
            short tmp[8];
#pragma unroll
            for (int i = 0; i < 8; i++) {
                int k = kc * 32 + lk * 8 + i;
                tmp[i] = (short)f2bf(aL[k] * Wt[k * 64 + o]);
            }
            bfrag[ct][kc] = *(bf16x8*)tmp;
        }
    }
    float bias[4];
#pragma unroll
    for (int ct = 0; ct < 4; ct++) bias[ct] = biasL[ct * 16 + lrow];

    for (int nc = blockIdx.x; nc < N_PAD / 64; nc += gridDim.x) {
        int n0 = nc * 64;
        int nw = n0 + wid * 16;
        f32x4 acc[4];
#pragma unroll
        for (int ct = 0; ct < 4; ct++)
            acc[ct] = {bias[ct], bias[ct], bias[ct], bias[ct]};
#pragma unroll
        for (int kc = 0; kc < 8; kc++) {
            bf16x8 a = *(const bf16x8*)(hbf + (size_t)(nw + lrow) * 256 + kc * 32 + lk * 8);
#pragma unroll
            for (int ct = 0; ct < 4; ct++)
                acc[ct] = __builtin_amdgcn_mfma_f32_16x16x32_bf16(a, bfrag[ct][kc], acc[ct], 0, 0, 0);
        }
#pragma unroll
        for (int ct = 0; ct < 4; ct++) {
            int c = ct * 16 + lrow;
#pragma unroll
            for (int r = 0; r < 4; r++) {
                int n = nw + lk * 4 + r;
                float v = fmaxf(acc[ct][r], 0.f);
                xt[wid * 16 + lk * 4 + r][c] = v;
                if (n < N_NODES) xbf[(size_t)n * 64 + c] = f2bf(v);
            }
        }
        __syncthreads();
        // segmented per-graph pooling over this 64-row tile
        int g0 = (n0 * 64) / 20000;
        int b = ((20000 * (g0 + 1) + 63) >> 6) - n0;
        if (b > 64) b = 64;
        {
            int ch = t & 63, rp = t >> 6;
            float mx0 = 0.f, sm0 = 0.f, mx1 = 0.f, sm1 = 0.f;
            for (int r = rp * 16; r < rp * 16 + 16; r++) {
                if (n0 + r < N_NODES) {
                    float v = xt[r][ch];
                    if (r < b) { mx0 = fmaxf(mx0, v); sm0 += v; }
                    else       { mx1 = fmaxf(mx1, v); sm1 += v; }
                }
            }
            red[rp][0][0][ch] = mx0; red[rp][0][1][ch] = sm0;
            red[rp][1][0][ch] = mx1; red[rp][1][1][ch] = sm1;
        }
        __syncthreads();
        if (t < 128) {
            int seg = t >> 6, ch = t & 63;
            float m = red[0][seg][0][ch], s = red[0][seg][1][ch];
#pragma unroll
            for (int w = 1; w < 4; w++) {
                m = fmaxf(m, red[w][seg][0][ch]);
                s += red[w][seg][1][ch];
            }
            int g = g0 + seg;
            bool valid = (seg == 0) || (b < 64 && g < NGRAPH);
            if (valid) {
                atomicMax((unsigned int*)&poolmx[(layer * NGRAPH + g) * 64 + ch],
                          __float_as_uint(m));
                atomicAdd(&poolsm[(layer * NGRAPH + g) * 64 + ch], s);
            }
        }
        __syncthreads();
    }
}

// ---------------- fused MLP head ----------------
__global__ __launch_bounds__(256) void head_kernel(
    const float* __restrict__ poolmx, const float* __restrict__ poolsm,
    const float* __restrict__ W1, const float* __restrict__ b1,
    const float* __restrict__ W2, const float* __restrict__ b2,
    const float* __restrict__ W3, const float* __restrict__ b3,
    float* __restrict__ out) {
    int g = blockIdx.x, t = threadIdx.x;
    __shared__ float repL[128], o1sh[256], o2sh[128];
    if (t < 128) {
        int d = t & 63;
        int start = (N_NODES * g + 63) >> 6;
        int end = (N_NODES * (g + 1) + 63) >> 6;
        float v = 0.f;
        if (t < 64) {
#pragma unroll
            for (int l = 0; l < NLAYER; l++) v += poolmx[(l * NGRAPH + g) * 64 + d];
        } else {
            float inv = 1.f / (float)(end - start);
#pragma unroll
            for (int l = 0; l < NLAYER; l++) v += poolsm[(l * NGRAPH + g) * 64 + d] * inv;
        }
        repL[t] = v;
    }
    __syncthreads();
    float a1 = b1[t];
    for (int k = 0; k < 128; k++) a1 += repL[k] * W1[k * 256 + t];
    o1sh[t] = fmaxf(a1, 0.f);
    __syncthreads();
    if (t < 128) {
        float a2 = b2[t];
        for (int k = 0; k < 256; k++) a2 += o1sh[k] * W2[k * 128 + t];
        o2sh[t] = fmaxf(a2, 0.f);
    }
    __syncthreads();
    if (t < 64) {
        float p = o2sh[t] * W3[t] + o2sh[t + 64] * W3[t + 64];
#pragma unroll
        for (int off = 32; off; off >>= 1) p += __shfl_xor(p, off);
        if (t == 0) out[g] = p + b3[0];
    }
}

extern "C" void kernel_launch(void* const* d_in, const int* in_sizes, int n_in,
                              void* d_out, int out_size, void* d_ws, size_t ws_size,
                              hipStream_t stream) {
    const float* x         = (const float*)d_in[0];
    const float* edge_attr = (const float*)d_in[1];
    const int*   ei        = (const int*)d_in[2];
    const float* Wq  = (const float*)d_in[4];
    const float* bq  = (const float*)d_in[5];
    const float* Wk  = (const float*)d_in[6];
    const float* bk  = (const float*)d_in[7];
    const float* Wv  = (const float*)d_in[8];
    const float* bv  = (const float*)d_in[9];
    const float* We  = (const float*)d_in[10];
    const float* Wsk = (const float*)d_in[11];
    const float* bsk = (const float*)d_in[12];
    const float* gam = (const float*)d_in[13];
    const float* bet = (const float*)d_in[14];
    const float* Wt  = (const float*)d_in[15];
    const float* bt  = (const float*)d_in[16];
    const float* W1  = (const float*)d_in[17];
    const float* b1  = (const float*)d_in[18];
    const float* W2  = (const float*)d_in[19];
    const float* b2  = (const float*)d_in[20];
    const float* W3  = (const float*)d_in[21];
    const float* b3  = (const float*)d_in[22];
    float* out = (float*)d_out;

    char* ws = (char*)d_ws;
    size_t off = 0;
    auto alloc = [&](size_t bytes) -> char* {
        char* p = ws + off;
        off += (bytes + 255) & ~(size_t)255;
        return p;
    };
    int*   rowptr = (int*)alloc((N_NODES + 1) * sizeof(int));
    int*   eidx   = (int*)alloc((size_t)N_EDGES * sizeof(int));
    int*   esrc   = (int*)alloc(((size_t)N_EDGES + 64) * sizeof(int));
    unsigned short* qbf  = (unsigned short*)alloc((size_t)N_NODES * 256 * 2);
    unsigned char*  kvf8 = (unsigned char*)alloc((size_t)N_NODES * 512);
    unsigned short* sbf  = (unsigned short*)alloc((size_t)N_NODES * 256 * 2);
    unsigned short* ubf  = (unsigned short*)alloc((size_t)N_NODES * 256 * 2);
    unsigned short* hbf  = (unsigned short*)alloc((size_t)N_PAD * 256 * 2);
    unsigned short* xbf  = (unsigned short*)alloc((size_t)N_PAD * 64 * 2);
    unsigned short* WallT = (unsigned short*)alloc((size_t)NLAYER * 81920 * 2);
    float* ball   = (float*)alloc((size_t)NLAYER * 1280 * sizeof(float));
    // ---- contiguous zero-init region (one memset per launch) ----
    size_t zero_off = off;
    int*   cur1   = (int*)alloc(N_NODES * sizeof(int));
    int*   cur2   = (int*)alloc(N_NODES * sizeof(int));
    float* statsA = (float*)alloc((size_t)NLAYER * 8 * 512 * sizeof(float));
    float* poolmx = (float*)alloc((size_t)NLAYER * NGRAPH * 64 * sizeof(float));
    float* poolsm = (float*)alloc((size_t)NLAYER * NGRAPH * 64 * sizeof(float));
    size_t zero_bytes = off - zero_off;
    // ---- optional permuted bf16 edge_attr ----
    unsigned short* eaPb = (unsigned short*)alloc((size_t)N_EDGES * 64 * 2);
    bool perm = (off <= ws_size);

    hipMemsetAsync(ws + zero_off, 0, zero_bytes, stream);

    count_kernel<<<(N_EDGES + 255) / 256, 256, 0, stream>>>(ei, cur1);
    scan_kernel<<<1, 256, 0, stream>>>(cur1, rowptr);
    fill_kernel<<<(N_EDGES + 255) / 256, 256, 0, stream>>>(ei, rowptr, cur2, eidx, esrc);
    if (perm) {
        permute_ea_b_kernel<<<(N_EDGES * 16 + 255) / 256, 256, 0, stream>>>(
            edge_attr, eidx, eaPb);
    }

    prep_kernel<<<1280 * NLAYER + (N_PAD * 16 + 63) / 64, 64, 0, stream>>>(
        Wq, Wk, Wv, Wsk, We, bq, bk, bv, bsk, x, WallT, ball, xbf);

    for (int i = 0; i < NLAYER; i++) {
        gemm_qkvsu4_kernel<<<dim3(79, 10), 256, 0, stream>>>(
            xbf, WallT + (size_t)i * 81920, ball + i * 1280, qbf, kvf8, sbf, ubf);

        attn12_kernel<<<2500, 256, 0, stream>>>(
            perm ? eaPb : (const unsigned short*)nullptr, edge_attr,
            eidx, rowptr, esrc, qbf, ubf, kvf8, sbf,
            We + i * 16384, hbf, statsA + (size_t)i * 4096);

        xform5_kernel<<<157, 256, 0, stream>>>(
            hbf, Wt + i * 16384, gam + i * 256, bet + i * 256, bt + i * 64,
            statsA + (size_t)i * 4096, xbf, poolmx, poolsm, i);
    }

    head_kernel<<<64, 256, 0, stream>>>(poolmx, poolsm, W1, b1, W2, b2, W3, b3, out);
}

// Round 12
// 583.343 us; speedup vs baseline: 1.1375x; 1.1375x over previous
//
#include <hip/hip_runtime.h>
#include <math.h>
#include <float.h>

#define N_NODES 20000
#define N_PAD 20032          // 313*64
#define N_EDGES 320000
#define NGRAPH 64
#define NLAYER 3
#define BN_EPS 1e-5f

typedef short bf16x8 __attribute__((ext_vector_type(8)));
typedef float f32x4 __attribute__((ext_vector_type(4)));

__device__ inline unsigned short f2bf(float f) {
    unsigned int u = __float_as_uint(f);
    unsigned int r = u + 0x7FFF + ((u >> 16) & 1);   // RNE
    return (unsigned short)(r >> 16);
}
__device__ inline float bf2f(unsigned short s) {
    return __uint_as_float((unsigned int)s << 16);
}

// ---------------- CSR construction ----------------
__global__ void count_kernel(const int* __restrict__ ei, int* __restrict__ cnt) {
    int e = blockIdx.x * blockDim.x + threadIdx.x;
    if (e < N_EDGES) atomicAdd(&cnt[ei[N_EDGES + e]], 1);
}

__global__ void scan_kernel(const int* __restrict__ cnt, int* __restrict__ rowptr) {
    __shared__ int sh[256];
    int t = threadIdx.x;
    const int CH = (N_NODES + 255) / 256;
    int base = t * CH;
    int s = 0;
    for (int i = 0; i < CH; i++) { int idx = base + i; if (idx < N_NODES) s += cnt[idx]; }
    sh[t] = s;
    __syncthreads();
    for (int off = 1; off < 256; off <<= 1) {
        int v = sh[t];
        int add = (t >= off) ? sh[t - off] : 0;
        __syncthreads();
        sh[t] = v + add;
        __syncthreads();
    }
    int run = sh[t] - s;
    for (int i = 0; i < CH; i++) {
        int idx = base + i;
        if (idx < N_NODES) { rowptr[idx] = run; run += cnt[idx]; }
    }
    if (t == 255) rowptr[N_NODES] = sh[255];
}

__global__ void fill_kernel(const int* __restrict__ ei, const int* __restrict__ rowptr,
                            int* __restrict__ cur, int* __restrict__ eidx,
                            int* __restrict__ esrc) {
    int e = blockIdx.x * blockDim.x + threadIdx.x;
    if (e < N_EDGES) {
        int dst = ei[N_EDGES + e];
        int pos = atomicAdd(&cur[dst], 1);
        int slot = rowptr[dst] + pos;
        eidx[slot] = e;
        esrc[slot] = ei[e];
    }
}

// permute edge_attr into CSR order, converting to bf16
__global__ void permute_ea_b_kernel(const float* __restrict__ edge_attr,
                                    const int* __restrict__ eidx,
                                    unsigned short* __restrict__ eaPb) {
    int idx = blockIdx.x * blockDim.x + threadIdx.x;   // quad index
    if (idx < N_EDGES * 16) {
        int j = idx >> 4, c4 = idx & 15;
        float4 v = *(const float4*)(edge_attr + (size_t)eidx[j] * 64 + c4 * 4);
        ((ushort4*)eaPb)[idx] = make_ushort4(f2bf(v.x), f2bf(v.y), f2bf(v.z), f2bf(v.w));
    }
}

// ---------------- build transposed bf16 weight panel [L][1280][64] + bias [L][1280] ----
// seg 4 (u) computes the We-fold on the fly: Wu[k,h,d] = sum_c Wq[k,h,c]*We[d,h,c]
__global__ void wallt2_kernel(const float* __restrict__ Wq, const float* __restrict__ Wk,
                              const float* __restrict__ Wv, const float* __restrict__ Ws,
                              const float* __restrict__ We,
                              const float* __restrict__ bq, const float* __restrict__ bk,
                              const float* __restrict__ bv, const float* __restrict__ bs,
                              unsigned short* __restrict__ WallT, float* __restrict__ ball) {
    int c = blockIdx.x, l = blockIdx.y, k = threadIdx.x;
    int seg = c >> 8, ci = c & 255;
    if (seg < 4) {
        const float* W; const float* b;
        switch (seg) {
            case 0:  W = Wq; b = bq; break;
            case 1:  W = Wk; b = bk; break;
            case 2:  W = Wv; b = bv; break;
            default: W = Ws; b = bs; break;
        }
        WallT[(size_t)l * 81920 + c * 64 + k] = f2bf(W[l * 16384 + k * 256 + ci]);
        if (k == 0) ball[l * 1280 + c] = b[l * 256 + ci];
    } else {
        int h = ci >> 6, d = ci & 63;
        const float* Wql = Wq + l * 16384;
        const float* Wel = We + l * 16384;
        float acc = 0.f;
        for (int cc = 0; cc < 64; cc++)
            acc += Wql[k * 256 + h * 64 + cc] * Wel[d * 256 + h * 64 + cc];
        WallT[(size_t)l * 81920 + c * 64 + k] = f2bf(acc);
        if (k == 0) {
            const float* bql = bq + l * 256;
            float ab = 0.f;
            for (int cc = 0; cc < 64; cc++) ab += bql[h * 64 + cc] * Wel[d * 256 + h * 64 + cc];
            ball[l * 1280 + c] = ab;
        }
    }
}

// ---------------- x -> bf16 (padded to N_PAD rows) ----------------
__global__ void xtobf_kernel(const float* __restrict__ x, unsigned short* __restrict__ xbf) {
    int i4 = blockIdx.x * 256 + threadIdx.x;
    if (i4 >= N_PAD * 64 / 4) return;
    int n = i4 >> 4;
    ushort4 o;
    if (n < N_NODES) {
        float4 v = ((const float4*)x)[i4];
        o = make_ushort4(f2bf(v.x), f2bf(v.y), f2bf(v.z), f2bf(v.w));
    } else o = make_ushort4(0, 0, 0, 0);
    ((ushort4*)xbf)[i4] = o;
}

// ---------------- fused 5-way node linear via MFMA; k/v packed fp8 -------------------
__global__ __launch_bounds__(256) void gemm_qkvsu4_kernel(
    const unsigned short* __restrict__ xbf,     // [N_PAD][64]
    const unsigned short* __restrict__ WallT,   // [1280][64] layer slice
    const float* __restrict__ ball,             // [1280]
    unsigned short* __restrict__ qbf, unsigned char* __restrict__ kvf8,
    unsigned short* __restrict__ sbf, unsigned short* __restrict__ ubf) {
    int t = threadIdx.x, wid = t >> 6, lane = t & 63;
    int lrow = lane & 15, lk = lane >> 4;

    bf16x8 bfrag[2][4][2];
    float bias[2][4];
    int kind[2];                 // 0 = bf16 out, 1 = fp8 k, 2 = fp8 v
    unsigned short* outb[2]; int obase[2];
#pragma unroll
    for (int cg = 0; cg < 2; cg++) {
        int ys = blockIdx.y * 2 + cg;
        int col0 = ys * 64;
        int q = ys & 3;
        if (ys < 4)       { kind[cg] = 0; outb[cg] = qbf; obase[cg] = q * 64; }
        else if (ys < 8)  { kind[cg] = 1; outb[cg] = nullptr; obase[cg] = q * 64; }
        else if (ys < 12) { kind[cg] = 2; outb[cg] = nullptr; obase[cg] = q * 64; }
        else if (ys < 16) { kind[cg] = 0; outb[cg] = sbf; obase[cg] = q * 64; }
        else              { kind[cg] = 0; outb[cg] = ubf; obase[cg] = q * 64; }
#pragma unroll
        for (int ct = 0; ct < 4; ct++) {
#pragma unroll
            for (int kc = 0; kc < 2; kc++)
                bfrag[cg][ct][kc] = *(const bf16x8*)(WallT +
                    (size_t)(col0 + ct * 16 + lrow) * 64 + kc * 32 + lk * 8);
            bias[cg][ct] = ball[col0 + ct * 16 + lrow];
        }
    }

    for (int nc = blockIdx.x; nc < N_PAD / 64; nc += gridDim.x) {
        int n0 = nc * 64 + wid * 16;
        bf16x8 a0 = *(const bf16x8*)(xbf + (size_t)(n0 + lrow) * 64 + lk * 8);
        bf16x8 a1 = *(const bf16x8*)(xbf + (size_t)(n0 + lrow) * 64 + 32 + lk * 8);
#pragma unroll
        for (int cg = 0; cg < 2; cg++) {
#pragma unroll
            for (int ct = 0; ct < 4; ct++) {
                f32x4 acc = {bias[cg][ct], bias[cg][ct], bias[cg][ct], bias[cg][ct]};
                acc = __builtin_amdgcn_mfma_f32_16x16x32_bf16(a0, bfrag[cg][ct][0], acc, 0, 0, 0);
                acc = __builtin_amdgcn_mfma_f32_16x16x32_bf16(a1, bfrag[cg][ct][1], acc, 0, 0, 0);
                int cl = ct * 16 + lrow;
#pragma unroll
                for (int r = 0; r < 4; r++) {
                    int n = n0 + lk * 4 + r;
                    if (n < N_NODES) {
                        if (kind[cg] == 0) {
                            outb[cg][(size_t)n * 256 + obase[cg] + cl] = f2bf(acc[r]);
                        } else {
                            unsigned int pk = __builtin_amdgcn_cvt_pk_fp8_f32(
                                acc[r], acc[r], 0, false);
                            int ch = obase[cg] + cl;
                            kvf8[(size_t)n * 512 + 2 * ch + (kind[cg] - 1)] =
                                (unsigned char)pk;
                        }
                    }
                }
            }
        }
    }
}

// ---------------- lean fused attention: esrc lane-batched, SGPR gather addresses -----
__global__ __launch_bounds__(256) void attn10_kernel(
    const unsigned short* __restrict__ eaPb,  // bf16 CSR-ordered, or NULL
    const float* __restrict__ ea_f32,         // fallback: original fp32
    const int* __restrict__ eaidx,            // fallback index
    const int* __restrict__ rowptr, const int* __restrict__ esrc,
    const unsigned short* __restrict__ qbf, const unsigned short* __restrict__ ubf,
    const unsigned char* __restrict__ kvf8,   // [n][512]B: byte 2c=k[c], 2c+1=v[c]
    const unsigned short* __restrict__ sbf,
    unsigned short* __restrict__ hskb,        // out: bf16(acc + skip)
    unsigned short* __restrict__ raccb) {     // out: bf16 softmax-weighted ea sum
    int t = threadIdx.x;
    int wid = t >> 6, lane = t & 63;
    int c4 = lane * 4;
    int ec4 = (lane & 15) * 4;
    for (int n = blockIdx.x * 4 + wid; n < N_NODES; n += gridDim.x * 4) {
        ushort4 qu = *(const ushort4*)(qbf + (size_t)n * 256 + c4);
        ushort4 uu = *(const ushort4*)(ubf + (size_t)n * 256 + c4);
        float4 q4 = make_float4(bf2f(qu.x), bf2f(qu.y), bf2f(qu.z), bf2f(qu.w));
        float4 u4 = make_float4(bf2f(uu.x), bf2f(uu.y), bf2f(uu.z), bf2f(uu.w));
        int j0 = rowptr[n];
        int cnt = rowptr[n + 1] - j0;
        float l = 0.f;
        float4 a4 = make_float4(0.f, 0.f, 0.f, 0.f), r4 = a4;

        for (int base = 0; base < cnt; base += 64) {
            int nb = cnt - base;
            if (nb > 64) nb = 64;
            int jb = j0 + base;
            // one vector load fetches all edge sources of this batch
            int srcv = (lane < nb) ? esrc[jb + lane] : 0;
            uint2 kvA = make_uint2(0, 0), kvB = kvA;
            float4 eA = make_float4(0.f, 0.f, 0.f, 0.f), eB = eA;

#define LOADE(KV, EV, JJ) do { \
        int _s = __builtin_amdgcn_readlane(srcv, (JJ)); \
        KV = *(const uint2*)(kvf8 + (size_t)_s * 512 + c4 * 2); \
        int _j = jb + (JJ); \
        if (eaPb) { ushort4 _e = *(const ushort4*)(eaPb + (size_t)_j * 64 + ec4); \
                    EV = make_float4(bf2f(_e.x), bf2f(_e.y), bf2f(_e.z), bf2f(_e.w)); } \
        else { float4 _f = *(const float4*)(ea_f32 + (size_t)eaidx[_j] * 64 + ec4); \
               EV = _f; } \
    } while (0)

#define PROC(KV, EV) do { \
        float K0 = __builtin_amdgcn_cvt_f32_fp8(KV.x, 0); \
        float V0 = __builtin_amdgcn_cvt_f32_fp8(KV.x, 1); \
        float K1 = __builtin_amdgcn_cvt_f32_fp8(KV.x, 2); \
        float V1 = __builtin_amdgcn_cvt_f32_fp8(KV.x, 3); \
        float K2 = __builtin_amdgcn_cvt_f32_fp8(KV.y, 0); \
        float V2 = __builtin_amdgcn_cvt_f32_fp8(KV.y, 1); \
        float K3 = __builtin_amdgcn_cvt_f32_fp8(KV.y, 2); \
        float V3 = __builtin_amdgcn_cvt_f32_fp8(KV.y, 3); \
        float p = q4.x * K0 + q4.y * K1 + q4.z * K2 + q4.w * K3 \
                + u4.x * EV.x + u4.y * EV.y + u4.z * EV.z + u4.w * EV.w; \
        p += __shfl_xor(p, 1); p += __shfl_xor(p, 2); \
        p += __shfl_xor(p, 4); p += __shfl_xor(p, 8); \
        p = __expf(p * 0.125f); \
        l += p; \
        a4.x += p * V0; a4.y += p * V1; a4.z += p * V2; a4.w += p * V3; \
        r4.x += p * EV.x; r4.y += p * EV.y; r4.z += p * EV.z; r4.w += p * EV.w; \
    } while (0)

            if (nb > 0) LOADE(kvA, eA, 0);
            if (nb > 1) LOADE(kvB, eB, 1);
            int jj = 0;
            for (; jj + 1 < nb; jj += 2) {
                uint2 kv0 = kvA; float4 e0 = eA;
                if (jj + 2 < nb) LOADE(kvA, eA, jj + 2);
                PROC(kv0, e0);
                uint2 kv1 = kvB; float4 e1 = eB;
                if (jj + 3 < nb) LOADE(kvB, eB, jj + 3);
                PROC(kv1, e1);
            }
            if (jj < nb) PROC(kvA, eA);
#undef LOADE
#undef PROC
        }
        float inv = (l > 0.f) ? 1.f / l : 0.f;
        ushort4 su = *(const ushort4*)(sbf + (size_t)n * 256 + c4);
        *(ushort4*)(hskb + (size_t)n * 256 + c4) = make_ushort4(
            f2bf(a4.x * inv + bf2f(su.x)), f2bf(a4.y * inv + bf2f(su.y)),
            f2bf(a4.z * inv + bf2f(su.z)), f2bf(a4.w * inv + bf2f(su.w)));
        *(ushort4*)(raccb + (size_t)n * 256 + c4) = make_ushort4(
            f2bf(r4.x * inv), f2bf(r4.y * inv), f2bf(r4.z * inv), f2bf(r4.w * inv));
    }
}

// ---------------- msg = racc @ We (block-diag per head); h = hsk+msg -> hbf + BN stats
__global__ __launch_bounds__(256) void msgbn2_kernel(
    const unsigned short* __restrict__ raccb, const float* __restrict__ We,
    const unsigned short* __restrict__ hskb, unsigned short* __restrict__ hbf,
    float* __restrict__ statsL) {
    int t = threadIdx.x;
    float wcol[64];
#pragma unroll
    for (int d = 0; d < 64; d++) wcol[d] = We[d * 256 + t];
    int hoff = t & 192;
    float s = 0.f, s2 = 0.f;
    for (int n = blockIdx.x * 4; n < N_NODES; n += gridDim.x * 4) {
#pragma unroll
        for (int ni = 0; ni < 4; ni++) {
            const unsigned short* rrow = raccb + (size_t)(n + ni) * 256 + hoff;
            float acc = 0.f;
#pragma unroll
            for (int d4 = 0; d4 < 64; d4 += 4) {
                ushort4 r4 = *(const ushort4*)(rrow + d4);
                acc += bf2f(r4.x) * wcol[d4] + bf2f(r4.y) * wcol[d4 + 1]
                     + bf2f(r4.z) * wcol[d4 + 2] + bf2f(r4.w) * wcol[d4 + 3];
            }
            float hv = bf2f(hskb[(size_t)(n + ni) * 256 + t]) + acc;
            hbf[(size_t)(n + ni) * 256 + t] = f2bf(hv);
            s += hv; s2 += hv * hv;
        }
    }
    int base = (blockIdx.x & 7) * 512;
    atomicAdd(&statsL[base + t], s);
    atomicAdd(&statsL[base + 256 + t], s2);
}

// ---------------- x = relu(BN(h) @ Wt + bt): BN-fold computed in-block, MFMA, pooling -
__global__ __launch_bounds__(256) void xform5_kernel(
    const unsigned short* __restrict__ hbf,     // [N_PAD][256]
    const float* __restrict__ Wt,               // [256][64] raw fp32 layer slice
    const float* __restrict__ gamma, const float* __restrict__ beta,
    const float* __restrict__ bt,
    const float* __restrict__ statsL,           // [8][512]
    unsigned short* __restrict__ xbf,           // [N_PAD][64]
    float* __restrict__ poolmx, float* __restrict__ poolsm, int layer) {
    __shared__ float xt[64][65];
    __shared__ float red[4][2][2][64];
    __shared__ float aL[256], bbL[256], partb[256], biasL[64];
    int t = threadIdx.x, wid = t >> 6, lane = t & 63;
    int lrow = lane & 15, lk = lane >> 4;

    // ---- BN fold (redundant per block; cheap) ----
    {
        float sum = 0.f, sq = 0.f;
#pragma unroll
        for (int s = 0; s < 8; s++) {
            sum += statsL[s * 512 + t];
            sq  += statsL[s * 512 + 256 + t];
        }
        float mean = sum * (1.f / N_NODES);
        float var = sq * (1.f / N_NODES) - mean * mean;
        float a = rsqrtf(var + BN_EPS) * gamma[t];
        aL[t] = a;
        bbL[t] = beta[t] - mean * a;
    }
    __syncthreads();
    {
        float p = 0.f;
        int o = t & 63, kq = (t >> 6) * 64;
        for (int kk = kq; kk < kq + 64; kk++) p += bbL[kk] * Wt[kk * 64 + o];
        partb[t] = p;
    }
    __syncthreads();
    if (t < 64) biasL[t] = bt[t] + partb[t] + partb[64 + t] + partb[128 + t] + partb[192 + t];
    __syncthreads();

    // ---- folded bf16 B fragments ----
    bf16x8 bfrag[4][8];
#pragma unroll
    for (int ct = 0; ct < 4; ct++) {
        int o = ct * 16 + lrow;
#pragma unroll
        for (int kc = 0; kc < 8; kc++) {
            short tmp[8];
#pragma unroll
            for (int i = 0; i < 8; i++) {
                int k = kc * 32 + lk * 8 + i;
                tmp[i] = (short)f2bf(aL[k] * Wt[k * 64 + o]);
            }
            bfrag[ct][kc] = *(bf16x8*)tmp;
        }
    }
    float bias[4];
#pragma unroll
    for (int ct = 0; ct < 4; ct++) bias[ct] = biasL[ct * 16 + lrow];

    for (int nc = blockIdx.x; nc < N_PAD / 64; nc += gridDim.x) {
        int n0 = nc * 64;
        int nw = n0 + wid * 16;
        f32x4 acc[4];
#pragma unroll
        for (int ct = 0; ct < 4; ct++)
            acc[ct] = {bias[ct], bias[ct], bias[ct], bias[ct]};
#pragma unroll
        for (int kc = 0; kc < 8; kc++) {
            bf16x8 a = *(const bf16x8*)(hbf + (size_t)(nw + lrow) * 256 + kc * 32 + lk * 8);
#pragma unroll
            for (int ct = 0; ct < 4; ct++)
                acc[ct] = __builtin_amdgcn_mfma_f32_16x16x32_bf16(a, bfrag[ct][kc], acc[ct], 0, 0, 0);
        }
#pragma unroll
        for (int ct = 0; ct < 4; ct++) {
            int c = ct * 16 + lrow;
#pragma unroll
            for (int r = 0; r < 4; r++) {
                int n = nw + lk * 4 + r;
                float v = fmaxf(acc[ct][r], 0.f);
                xt[wid * 16 + lk * 4 + r][c] = v;
                if (n < N_NODES) xbf[(size_t)n * 64 + c] = f2bf(v);
            }
        }
        __syncthreads();
        // segmented per-graph pooling over this 64-row tile
        int g0 = (n0 * 64) / 20000;
        int b = ((20000 * (g0 + 1) + 63) >> 6) - n0;
        if (b > 64) b = 64;
        {
            int ch = t & 63, rp = t >> 6;
            float mx0 = 0.f, sm0 = 0.f, mx1 = 0.f, sm1 = 0.f;
            for (int r = rp * 16; r < rp * 16 + 16; r++) {
                if (n0 + r < N_NODES) {
                    float v = xt[r][ch];
                    if (r < b) { mx0 = fmaxf(mx0, v); sm0 += v; }
                    else       { mx1 = fmaxf(mx1, v); sm1 += v; }
                }
            }
            red[rp][0][0][ch] = mx0; red[rp][0][1][ch] = sm0;
            red[rp][1][0][ch] = mx1; red[rp][1][1][ch] = sm1;
        }
        __syncthreads();
        if (t < 128) {
            int seg = t >> 6, ch = t & 63;
            float m = red[0][seg][0][ch], s = red[0][seg][1][ch];
#pragma unroll
            for (int w = 1; w < 4; w++) {
                m = fmaxf(m, red[w][seg][0][ch]);
                s += red[w][seg][1][ch];
            }
            int g = g0 + seg;
            bool valid = (seg == 0) || (b < 64 && g < NGRAPH);
            if (valid) {
                atomicMax((unsigned int*)&poolmx[(layer * NGRAPH + g) * 64 + ch],
                          __float_as_uint(m));
                atomicAdd(&poolsm[(layer * NGRAPH + g) * 64 + ch], s);
            }
        }
        __syncthreads();
    }
}

// ---------------- fused MLP head ----------------
__global__ __launch_bounds__(256) void head_kernel(
    const float* __restrict__ poolmx, const float* __restrict__ poolsm,
    const float* __restrict__ W1, const float* __restrict__ b1,
    const float* __restrict__ W2, const float* __restrict__ b2,
    const float* __restrict__ W3, const float* __restrict__ b3,
    float* __restrict__ out) {
    int g = blockIdx.x, t = threadIdx.x;
    __shared__ float repL[128], o1sh[256], o2sh[128];
    if (t < 128) {
        int d = t & 63;
        int start = (N_NODES * g + 63) >> 6;
        int end = (N_NODES * (g + 1) + 63) >> 6;
        float v = 0.f;
        if (t < 64) {
#pragma unroll
            for (int l = 0; l < NLAYER; l++) v += poolmx[(l * NGRAPH + g) * 64 + d];
        } else {
            float inv = 1.f / (float)(end - start);
#pragma unroll
            for (int l = 0; l < NLAYER; l++) v += poolsm[(l * NGRAPH + g) * 64 + d] * inv;
        }
        repL[t] = v;
    }
    __syncthreads();
    float a1 = b1[t];
    for (int k = 0; k < 128; k++) a1 += repL[k] * W1[k * 256 + t];
    o1sh[t] = fmaxf(a1, 0.f);
    __syncthreads();
    if (t < 128) {
        float a2 = b2[t];
        for (int k = 0; k < 256; k++) a2 += o1sh[k] * W2[k * 128 + t];
        o2sh[t] = fmaxf(a2, 0.f);
    }
    __syncthreads();
    if (t < 64) {
        float p = o2sh[t] * W3[t] + o2sh[t + 64] * W3[t + 64];
#pragma unroll
        for (int off = 32; off; off >>= 1) p += __shfl_xor(p, off);
        if (t == 0) out[g] = p + b3[0];
    }
}

extern "C" void kernel_launch(void* const* d_in, const int* in_sizes, int n_in,
                              void* d_out, int out_size, void* d_ws, size_t ws_size,
                              hipStream_t stream) {
    const float* x         = (const float*)d_in[0];
    const float* edge_attr = (const float*)d_in[1];
    const int*   ei        = (const int*)d_in[2];
    const float* Wq  = (const float*)d_in[4];
    const float* bq  = (const float*)d_in[5];
    const float* Wk  = (const float*)d_in[6];
    const float* bk  = (const float*)d_in[7];
    const float* Wv  = (const float*)d_in[8];
    const float* bv  = (const float*)d_in[9];
    const float* We  = (const float*)d_in[10];
    const float* Wsk = (const float*)d_in[11];
    const float* bsk = (const float*)d_in[12];
    const float* gam = (const float*)d_in[13];
    const float* bet = (const float*)d_in[14];
    const float* Wt  = (const float*)d_in[15];
    const float* bt  = (const float*)d_in[16];
    const float* W1  = (const float*)d_in[17];
    const float* b1  = (const float*)d_in[18];
    const float* W2  = (const float*)d_in[19];
    const float* b2  = (const float*)d_in[20];
    const float* W3  = (const float*)d_in[21];
    const float* b3  = (const float*)d_in[22];
    float* out = (float*)d_out;

    char* ws = (char*)d_ws;
    size_t off = 0;
    auto alloc = [&](size_t bytes) -> char* {
        char* p = ws + off;
        off += (bytes + 255) & ~(size_t)255;
        return p;
    };
    int*   rowptr = (int*)alloc((N_NODES + 1) * sizeof(int));
    int*   eidx   = (int*)alloc((size_t)N_EDGES * sizeof(int));
    int*   esrc   = (int*)alloc(((size_t)N_EDGES + 64) * sizeof(int));
    unsigned short* qbf  = (unsigned short*)alloc((size_t)N_NODES * 256 * 2);
    unsigned char*  kvf8 = (unsigned char*)alloc((size_t)N_NODES * 512);
    unsigned short* sbf  = (unsigned short*)alloc((size_t)N_NODES * 256 * 2);
    unsigned short* ubf  = (unsigned short*)alloc((size_t)N_NODES * 256 * 2);
    unsigned short* hskb = (unsigned short*)alloc((size_t)N_NODES * 256 * 2);
    unsigned short* raccb= (unsigned short*)alloc((size_t)N_NODES * 256 * 2);
    unsigned short* hbf  = (unsigned short*)alloc((size_t)N_PAD * 256 * 2);
    unsigned short* xbf  = (unsigned short*)alloc((size_t)N_PAD * 64 * 2);
    unsigned short* WallT = (unsigned short*)alloc((size_t)NLAYER * 81920 * 2);
    float* ball   = (float*)alloc((size_t)NLAYER * 1280 * sizeof(float));
    // ---- contiguous zero-init region (one memset per launch) ----
    size_t zero_off = off;
    int*   cur1   = (int*)alloc(N_NODES * sizeof(int));
    int*   cur2   = (int*)alloc(N_NODES * sizeof(int));
    float* statsA = (float*)alloc((size_t)NLAYER * 8 * 512 * sizeof(float));
    float* poolmx = (float*)alloc((size_t)NLAYER * NGRAPH * 64 * sizeof(float));
    float* poolsm = (float*)alloc((size_t)NLAYER * NGRAPH * 64 * sizeof(float));
    size_t zero_bytes = off - zero_off;
    // ---- optional permuted bf16 edge_attr ----
    unsigned short* eaPb = (unsigned short*)alloc((size_t)N_EDGES * 64 * 2);
    bool perm = (off <= ws_size);

    hipMemsetAsync(ws + zero_off, 0, zero_bytes, stream);

    count_kernel<<<(N_EDGES + 255) / 256, 256, 0, stream>>>(ei, cur1);
    scan_kernel<<<1, 256, 0, stream>>>(cur1, rowptr);
    fill_kernel<<<(N_EDGES + 255) / 256, 256, 0, stream>>>(ei, rowptr, cur2, eidx, esrc);
    if (perm) {
        permute_ea_b_kernel<<<(N_EDGES * 16 + 255) / 256, 256, 0, stream>>>(
            edge_attr, eidx, eaPb);
    }

    wallt2_kernel<<<dim3(1280, NLAYER), 64, 0, stream>>>(
        Wq, Wk, Wv, Wsk, We, bq, bk, bv, bsk, WallT, ball);
    xtobf_kernel<<<(N_PAD * 64 / 4 + 255) / 256, 256, 0, stream>>>(x, xbf);

    for (int i = 0; i < NLAYER; i++) {
        gemm_qkvsu4_kernel<<<dim3(79, 10), 256, 0, stream>>>(
            xbf, WallT + (size_t)i * 81920, ball + i * 1280, qbf, kvf8, sbf, ubf);

        attn10_kernel<<<2500, 256, 0, stream>>>(
            perm ? eaPb : (const unsigned short*)nullptr, edge_attr,
            eidx, rowptr, esrc, qbf, ubf, kvf8, sbf, hskb, raccb);

        msgbn2_kernel<<<1250, 256, 0, stream>>>(
            raccb, We + i * 16384, hskb, hbf, statsA + (size_t)i * 4096);

        xform5_kernel<<<157, 256, 0, stream>>>(
            hbf, Wt + i * 16384, gam + i * 256, bet + i * 256, bt + i * 64,
            statsA + (size_t)i * 4096, xbf, poolmx, poolsm, i);
    }

    head_kernel<<<64, 256, 0, stream>>>(poolmx, poolsm, W1, b1, W2, b2, W3, b3, out);
}

// Round 13
// 578.633 us; speedup vs baseline: 1.1467x; 1.0081x over previous
//
#include <hip/hip_runtime.h>
#include <math.h>
#include <float.h>

#define N_NODES 20000
#define N_PAD 20032          // 313*64
#define N_EDGES 320000
#define NGRAPH 64
#define NLAYER 3
#define BN_EPS 1e-5f

typedef short bf16x8 __attribute__((ext_vector_type(8)));
typedef float f32x4 __attribute__((ext_vector_type(4)));

__device__ inline unsigned short f2bf(float f) {
    unsigned int u = __float_as_uint(f);
    unsigned int r = u + 0x7FFF + ((u >> 16) & 1);   // RNE
    return (unsigned short)(r >> 16);
}
__device__ inline float bf2f(unsigned short s) {
    return __uint_as_float((unsigned int)s << 16);
}

// ---------------- CSR construction ----------------
__global__ void count_kernel(const int* __restrict__ ei, int* __restrict__ cnt) {
    int e = blockIdx.x * blockDim.x + threadIdx.x;
    if (e < N_EDGES) atomicAdd(&cnt[ei[N_EDGES + e]], 1);
}

__global__ void scan_kernel(const int* __restrict__ cnt, int* __restrict__ rowptr) {
    __shared__ int sh[256];
    int t = threadIdx.x;
    const int CH = (N_NODES + 255) / 256;
    int base = t * CH;
    int s = 0;
    for (int i = 0; i < CH; i++) { int idx = base + i; if (idx < N_NODES) s += cnt[idx]; }
    sh[t] = s;
    __syncthreads();
    for (int off = 1; off < 256; off <<= 1) {
        int v = sh[t];
        int add = (t >= off) ? sh[t - off] : 0;
        __syncthreads();
        sh[t] = v + add;
        __syncthreads();
    }
    int run = sh[t] - s;
    for (int i = 0; i < CH; i++) {
        int idx = base + i;
        if (idx < N_NODES) { rowptr[idx] = run; run += cnt[idx]; }
    }
    if (t == 255) rowptr[N_NODES] = sh[255];
}

__global__ void fill_kernel(const int* __restrict__ ei, const int* __restrict__ rowptr,
                            int* __restrict__ cur, int* __restrict__ eidx,
                            int* __restrict__ esrc) {
    int e = blockIdx.x * blockDim.x + threadIdx.x;
    if (e < N_EDGES) {
        int dst = ei[N_EDGES + e];
        int pos = atomicAdd(&cur[dst], 1);
        int slot = rowptr[dst] + pos;
        eidx[slot] = e;
        esrc[slot] = ei[e];
    }
}

// permute edge_attr into CSR order, converting to fp8 e4m3 (8 bytes per thread)
__global__ void permute_ea_8_kernel(const float* __restrict__ edge_attr,
                                    const int* __restrict__ eidx,
                                    unsigned char* __restrict__ eaP8) {
    int idx = blockIdx.x * blockDim.x + threadIdx.x;   // uint2 index (8 values)
    if (idx < N_EDGES * 8) {
        int j = idx >> 3, q = idx & 7;
        const float* src = edge_attr + (size_t)eidx[j] * 64 + q * 8;
        float4 v0 = *(const float4*)(src);
        float4 v1 = *(const float4*)(src + 4);
        unsigned int w0 = __builtin_amdgcn_cvt_pk_fp8_f32(v0.x, v0.y, 0, false);
        w0 = __builtin_amdgcn_cvt_pk_fp8_f32(v0.z, v0.w, w0, true);
        unsigned int w1 = __builtin_amdgcn_cvt_pk_fp8_f32(v1.x, v1.y, 0, false);
        w1 = __builtin_amdgcn_cvt_pk_fp8_f32(v1.z, v1.w, w1, true);
        ((uint2*)eaP8)[idx] = make_uint2(w0, w1);
    }
}

// ---------------- build transposed bf16 weight panel [L][1280][64] + bias [L][1280] ----
// seg 4 (u) computes the We-fold on the fly: Wu[k,h,d] = sum_c Wq[k,h,c]*We[d,h,c]
__global__ void wallt2_kernel(const float* __restrict__ Wq, const float* __restrict__ Wk,
                              const float* __restrict__ Wv, const float* __restrict__ Ws,
                              const float* __restrict__ We,
                              const float* __restrict__ bq, const float* __restrict__ bk,
                              const float* __restrict__ bv, const float* __restrict__ bs,
                              unsigned short* __restrict__ WallT, float* __restrict__ ball) {
    int c = blockIdx.x, l = blockIdx.y, k = threadIdx.x;
    int seg = c >> 8, ci = c & 255;
    if (seg < 4) {
        const float* W; const float* b;
        switch (seg) {
            case 0:  W = Wq; b = bq; break;
            case 1:  W = Wk; b = bk; break;
            case 2:  W = Wv; b = bv; break;
            default: W = Ws; b = bs; break;
        }
        WallT[(size_t)l * 81920 + c * 64 + k] = f2bf(W[l * 16384 + k * 256 + ci]);
        if (k == 0) ball[l * 1280 + c] = b[l * 256 + ci];
    } else {
        int h = ci >> 6, d = ci & 63;
        const float* Wql = Wq + l * 16384;
        const float* Wel = We + l * 16384;
        float acc = 0.f;
        for (int cc = 0; cc < 64; cc++)
            acc += Wql[k * 256 + h * 64 + cc] * Wel[d * 256 + h * 64 + cc];
        WallT[(size_t)l * 81920 + c * 64 + k] = f2bf(acc);
        if (k == 0) {
            const float* bql = bq + l * 256;
            float ab = 0.f;
            for (int cc = 0; cc < 64; cc++) ab += bql[h * 64 + cc] * Wel[d * 256 + h * 64 + cc];
            ball[l * 1280 + c] = ab;
        }
    }
}

// ---------------- x -> bf16 (padded to N_PAD rows) ----------------
__global__ void xtobf_kernel(const float* __restrict__ x, unsigned short* __restrict__ xbf) {
    int i4 = blockIdx.x * 256 + threadIdx.x;
    if (i4 >= N_PAD * 64 / 4) return;
    int n = i4 >> 4;
    ushort4 o;
    if (n < N_NODES) {
        float4 v = ((const float4*)x)[i4];
        o = make_ushort4(f2bf(v.x), f2bf(v.y), f2bf(v.z), f2bf(v.w));
    } else o = make_ushort4(0, 0, 0, 0);
    ((ushort4*)xbf)[i4] = o;
}

// ---------------- fused 5-way node linear via MFMA; k/v packed fp8 -------------------
__global__ __launch_bounds__(256) void gemm_qkvsu4_kernel(
    const unsigned short* __restrict__ xbf,     // [N_PAD][64]
    const unsigned short* __restrict__ WallT,   // [1280][64] layer slice
    const float* __restrict__ ball,             // [1280]
    unsigned short* __restrict__ qbf, unsigned char* __restrict__ kvf8,
    unsigned short* __restrict__ sbf, unsigned short* __restrict__ ubf) {
    int t = threadIdx.x, wid = t >> 6, lane = t & 63;
    int lrow = lane & 15, lk = lane >> 4;

    bf16x8 bfrag[2][4][2];
    float bias[2][4];
    int kind[2];                 // 0 = bf16 out, 1 = fp8 k, 2 = fp8 v
    unsigned short* outb[2]; int obase[2];
#pragma unroll
    for (int cg = 0; cg < 2; cg++) {
        int ys = blockIdx.y * 2 + cg;
        int col0 = ys * 64;
        int q = ys & 3;
        if (ys < 4)       { kind[cg] = 0; outb[cg] = qbf; obase[cg] = q * 64; }
        else if (ys < 8)  { kind[cg] = 1; outb[cg] = nullptr; obase[cg] = q * 64; }
        else if (ys < 12) { kind[cg] = 2; outb[cg] = nullptr; obase[cg] = q * 64; }
        else if (ys < 16) { kind[cg] = 0; outb[cg] = sbf; obase[cg] = q * 64; }
        else              { kind[cg] = 0; outb[cg] = ubf; obase[cg] = q * 64; }
#pragma unroll
        for (int ct = 0; ct < 4; ct++) {
#pragma unroll
            for (int kc = 0; kc < 2; kc++)
                bfrag[cg][ct][kc] = *(const bf16x8*)(WallT +
                    (size_t)(col0 + ct * 16 + lrow) * 64 + kc * 32 + lk * 8);
            bias[cg][ct] = ball[col0 + ct * 16 + lrow];
        }
    }

    for (int nc = blockIdx.x; nc < N_PAD / 64; nc += gridDim.x) {
        int n0 = nc * 64 + wid * 16;
        bf16x8 a0 = *(const bf16x8*)(xbf + (size_t)(n0 + lrow) * 64 + lk * 8);
        bf16x8 a1 = *(const bf16x8*)(xbf + (size_t)(n0 + lrow) * 64 + 32 + lk * 8);
#pragma unroll
        for (int cg = 0; cg < 2; cg++) {
#pragma unroll
            for (int ct = 0; ct < 4; ct++) {
                f32x4 acc = {bias[cg][ct], bias[cg][ct], bias[cg][ct], bias[cg][ct]};
                acc = __builtin_amdgcn_mfma_f32_16x16x32_bf16(a0, bfrag[cg][ct][0], acc, 0, 0, 0);
                acc = __builtin_amdgcn_mfma_f32_16x16x32_bf16(a1, bfrag[cg][ct][1], acc, 0, 0, 0);
                int cl = ct * 16 + lrow;
#pragma unroll
                for (int r = 0; r < 4; r++) {
                    int n = n0 + lk * 4 + r;
                    if (n < N_NODES) {
                        if (kind[cg] == 0) {
                            outb[cg][(size_t)n * 256 + obase[cg] + cl] = f2bf(acc[r]);
                        } else {
                            unsigned int pk = __builtin_amdgcn_cvt_pk_fp8_f32(
                                acc[r], acc[r], 0, false);
                            int ch = obase[cg] + cl;
                            kvf8[(size_t)n * 512 + 2 * ch + (kind[cg] - 1)] =
                                (unsigned char)pk;
                        }
                    }
                }
            }
        }
    }
}

// ---------------- lean fused attention: esrc lane-batched, fp8 kv + fp8 ea -----------
__global__ __launch_bounds__(256) void attn11_kernel(
    const unsigned char* __restrict__ eaP8,   // fp8 CSR-ordered, or NULL
    const float* __restrict__ ea_f32,         // fallback: original fp32
    const int* __restrict__ eaidx,            // fallback index
    const int* __restrict__ rowptr, const int* __restrict__ esrc,
    const unsigned short* __restrict__ qbf, const unsigned short* __restrict__ ubf,
    const unsigned char* __restrict__ kvf8,   // [n][512]B: byte 2c=k[c], 2c+1=v[c]
    const unsigned short* __restrict__ sbf,
    unsigned short* __restrict__ hskb,        // out: bf16(acc + skip)
    unsigned short* __restrict__ raccb) {     // out: bf16 softmax-weighted ea sum
    int t = threadIdx.x;
    int wid = t >> 6, lane = t & 63;
    int c4 = lane * 4;
    int ec4 = (lane & 15) * 4;
    for (int n = blockIdx.x * 4 + wid; n < N_NODES; n += gridDim.x * 4) {
        ushort4 qu = *(const ushort4*)(qbf + (size_t)n * 256 + c4);
        ushort4 uu = *(const ushort4*)(ubf + (size_t)n * 256 + c4);
        float4 q4 = make_float4(bf2f(qu.x), bf2f(qu.y), bf2f(qu.z), bf2f(qu.w));
        float4 u4 = make_float4(bf2f(uu.x), bf2f(uu.y), bf2f(uu.z), bf2f(uu.w));
        int j0 = rowptr[n];
        int cnt = rowptr[n + 1] - j0;
        float l = 0.f;
        float4 a4 = make_float4(0.f, 0.f, 0.f, 0.f), r4 = a4;

        for (int base = 0; base < cnt; base += 64) {
            int nb = cnt - base;
            if (nb > 64) nb = 64;
            int jb = j0 + base;
            // one vector load fetches all edge sources of this batch
            int srcv = (lane < nb) ? esrc[jb + lane] : 0;
            uint2 kvA = make_uint2(0, 0), kvB = kvA;
            float4 eA = make_float4(0.f, 0.f, 0.f, 0.f), eB = eA;

#define LOADE(KV, EV, JJ) do { \
        int _s = __builtin_amdgcn_readlane(srcv, (JJ)); \
        KV = *(const uint2*)(kvf8 + (size_t)_s * 512 + c4 * 2); \
        int _j = jb + (JJ); \
        if (eaP8) { unsigned int _e = *(const unsigned int*)(eaP8 + (size_t)_j * 64 + ec4); \
                    EV = make_float4(__builtin_amdgcn_cvt_f32_fp8(_e, 0), \
                                     __builtin_amdgcn_cvt_f32_fp8(_e, 1), \
                                     __builtin_amdgcn_cvt_f32_fp8(_e, 2), \
                                     __builtin_amdgcn_cvt_f32_fp8(_e, 3)); } \
        else { EV = *(const float4*)(ea_f32 + (size_t)eaidx[_j] * 64 + ec4); } \
    } while (0)

#define PROC(KV, EV) do { \
        float K0 = __builtin_amdgcn_cvt_f32_fp8(KV.x, 0); \
        float V0 = __builtin_amdgcn_cvt_f32_fp8(KV.x, 1); \
        float K1 = __builtin_amdgcn_cvt_f32_fp8(KV.x, 2); \
        float V1 = __builtin_amdgcn_cvt_f32_fp8(KV.x, 3); \
        float K2 = __builtin_amdgcn_cvt_f32_fp8(KV.y, 0); \
        float V2 = __builtin_amdgcn_cvt_f32_fp8(KV.y, 1); \
        float K3 = __builtin_amdgcn_cvt_f32_fp8(KV.y, 2); \
        float V3 = __builtin_amdgcn_cvt_f32_fp8(KV.y, 3); \
        float p = q4.x * K0 + q4.y * K1 + q4.z * K2 + q4.w * K3 \
                + u4.x * EV.x + u4.y * EV.y + u4.z * EV.z + u4.w * EV.w; \
        p += __shfl_xor(p, 1); p += __shfl_xor(p, 2); \
        p += __shfl_xor(p, 4); p += __shfl_xor(p, 8); \
        p = __expf(p * 0.125f); \
        l += p; \
        a4.x += p * V0; a4.y += p * V1; a4.z += p * V2; a4.w += p * V3; \
        r4.x += p * EV.x; r4.y += p * EV.y; r4.z += p * EV.z; r4.w += p * EV.w; \
    } while (0)

            if (nb > 0) LOADE(kvA, eA, 0);
            if (nb > 1) LOADE(kvB, eB, 1);
            int jj = 0;
            for (; jj + 1 < nb; jj += 2) {
                uint2 kv0 = kvA; float4 e0 = eA;
                if (jj + 2 < nb) LOADE(kvA, eA, jj + 2);
                PROC(kv0, e0);
                uint2 kv1 = kvB; float4 e1 = eB;
                if (jj + 3 < nb) LOADE(kvB, eB, jj + 3);
                PROC(kv1, e1);
            }
            if (jj < nb) PROC(kvA, eA);
#undef LOADE
#undef PROC
        }
        float inv = (l > 0.f) ? 1.f / l : 0.f;
        ushort4 su = *(const ushort4*)(sbf + (size_t)n * 256 + c4);
        *(ushort4*)(hskb + (size_t)n * 256 + c4) = make_ushort4(
            f2bf(a4.x * inv + bf2f(su.x)), f2bf(a4.y * inv + bf2f(su.y)),
            f2bf(a4.z * inv + bf2f(su.z)), f2bf(a4.w * inv + bf2f(su.w)));
        *(ushort4*)(raccb + (size_t)n * 256 + c4) = make_ushort4(
            f2bf(r4.x * inv), f2bf(r4.y * inv), f2bf(r4.z * inv), f2bf(r4.w * inv));
    }
}

// ---------------- msg = racc @ We (block-diag per head); h = hsk+msg -> hbf + BN stats
__global__ __launch_bounds__(256) void msgbn2_kernel(
    const unsigned short* __restrict__ raccb, const float* __restrict__ We,
    const unsigned short* __restrict__ hskb, unsigned short* __restrict__ hbf,
    float* __restrict__ statsL) {
    int t = threadIdx.x;
    float wcol[64];
#pragma unroll
    for (int d = 0; d < 64; d++) wcol[d] = We[d * 256 + t];
    int hoff = t & 192;
    float s = 0.f, s2 = 0.f;
    for (int n = blockIdx.x * 4; n < N_NODES; n += gridDim.x * 4) {
#pragma unroll
        for (int ni = 0; ni < 4; ni++) {
            const unsigned short* rrow = raccb + (size_t)(n + ni) * 256 + hoff;
            float acc = 0.f;
#pragma unroll
            for (int d4 = 0; d4 < 64; d4 += 4) {
                ushort4 r4 = *(const ushort4*)(rrow + d4);
                acc += bf2f(r4.x) * wcol[d4] + bf2f(r4.y) * wcol[d4 + 1]
                     + bf2f(r4.z) * wcol[d4 + 2] + bf2f(r4.w) * wcol[d4 + 3];
            }
            float hv = bf2f(hskb[(size_t)(n + ni) * 256 + t]) + acc;
            hbf[(size_t)(n + ni) * 256 + t] = f2bf(hv);
            s += hv; s2 += hv * hv;
        }
    }
    int base = (blockIdx.x & 7) * 512;
    atomicAdd(&statsL[base + t], s);
    atomicAdd(&statsL[base + 256 + t], s2);
}

// ---------------- x = relu(BN(h) @ Wt + bt): BN-fold computed in-block, MFMA, pooling -
__global__ __launch_bounds__(256) void xform5_kernel(
    const unsigned short* __restrict__ hbf,     // [N_PAD][256]
    const float* __restrict__ Wt,               // [256][64] raw fp32 layer slice
    const float* __restrict__ gamma, const float* __restrict__ beta,
    const float* __restrict__ bt,
    const float* __restrict__ statsL,           // [8][512]
    unsigned short* __restrict__ xbf,           // [N_PAD][64]
    float* __restrict__ poolmx, float* __restrict__ poolsm, int layer) {
    __shared__ float xt[64][65];
    __shared__ float red[4][2][2][64];
    __shared__ float aL[256], bbL[256], partb[256], biasL[64];
    int t = threadIdx.x, wid = t >> 6, lane = t & 63;
    int lrow = lane & 15, lk = lane >> 4;

    // ---- BN fold (redundant per block; cheap) ----
    {
        float sum = 0.f, sq = 0.f;
#pragma unroll
        for (int s = 0; s < 8; s++) {
            sum += statsL[s * 512 + t];
            sq  += statsL[s * 512 + 256 + t];
        }
        float mean = sum * (1.f / N_NODES);
        float var = sq * (1.f / N_NODES) - mean * mean;
        float a = rsqrtf(var + BN_EPS) * gamma[t];
        aL[t] = a;
        bbL[t] = beta[t] - mean * a;
    }
    __syncthreads();
    {
        float p = 0.f;
        int o = t & 63, kq = (t >> 6) * 64;
        for (int kk = kq; kk < kq + 64; kk++) p += bbL[kk] * Wt[kk * 64 + o];
        partb[t] = p;
    }
    __syncthreads();
    if (t < 64) biasL[t] = bt[t] + partb[t] + partb[64 + t] + partb[128 + t] + partb[192 + t];
    __syncthreads();

    // ---- folded bf16 B fragments ----
    bf16x8 bfrag[4][8];
#pragma unroll
    for (int ct = 0; ct < 4; ct++) {
        int o = ct * 16 + lrow;
#pragma unroll
        for (int kc = 0; kc < 8; kc++) {
            short tmp[8];
#pragma unroll
            for (int i = 0; i < 8; i++) {
                int k = kc * 32 + lk * 8 + i;
                tmp[i] = (short)f2bf(aL[k] * Wt[k * 64 + o]);
            }
            bfrag[ct][kc] = *(bf16x8*)tmp;
        }
    }
    float bias[4];
#pragma unroll
    for (int ct = 0; ct < 4; ct++) bias[ct] = biasL[ct * 16 + lrow];

    for (int nc = blockIdx.x; nc < N_PAD / 64; nc += gridDim.x) {
        int n0 = nc * 64;
        int nw = n0 + wid * 16;
        f32x4 acc[4];
#pragma unroll
        for (int ct = 0; ct < 4; ct++)
            acc[ct] = {bias[ct], bias[ct], bias[ct], bias[ct]};
#pragma unroll
        for (int kc = 0; kc < 8; kc++) {
            bf16x8 a = *(const bf16x8*)(hbf + (size_t)(nw + lrow) * 256 + kc * 32 + lk * 8);
#pragma unroll
            for (int ct = 0; ct < 4; ct++)
                acc[ct] = __builtin_amdgcn_mfma_f32_16x16x32_bf16(a, bfrag[ct][kc], acc[ct], 0, 0, 0);
        }
#pragma unroll
        for (int ct = 0; ct < 4; ct++) {
            int c = ct * 16 + lrow;
#pragma unroll
            for (int r = 0; r < 4; r++) {
                int n = nw + lk * 4 + r;
                float v = fmaxf(acc[ct][r], 0.f);
                xt[wid * 16 + lk * 4 + r][c] = v;
                if (n < N_NODES) xbf[(size_t)n * 64 + c] = f2bf(v);
            }
        }
        __syncthreads();
        // segmented per-graph pooling over this 64-row tile
        int g0 = (n0 * 64) / 20000;
        int b = ((20000 * (g0 + 1) + 63) >> 6) - n0;
        if (b > 64) b = 64;
        {
            int ch = t & 63, rp = t >> 6;
            float mx0 = 0.f, sm0 = 0.f, mx1 = 0.f, sm1 = 0.f;
            for (int r = rp * 16; r < rp * 16 + 16; r++) {
                if (n0 + r < N_NODES) {
                    float v = xt[r][ch];
                    if (r < b) { mx0 = fmaxf(mx0, v); sm0 += v; }
                    else       { mx1 = fmaxf(mx1, v); sm1 += v; }
                }
            }
            red[rp][0][0][ch] = mx0; red[rp][0][1][ch] = sm0;
            red[rp][1][0][ch] = mx1; red[rp][1][1][ch] = sm1;
        }
        __syncthreads();
        if (t < 128) {
            int seg = t >> 6, ch = t & 63;
            float m = red[0][seg][0][ch], s = red[0][seg][1][ch];
#pragma unroll
            for (int w = 1; w < 4; w++) {
                m = fmaxf(m, red[w][seg][0][ch]);
                s += red[w][seg][1][ch];
            }
            int g = g0 + seg;
            bool valid = (seg == 0) || (b < 64 && g < NGRAPH);
            if (valid) {
                atomicMax((unsigned int*)&poolmx[(layer * NGRAPH + g) * 64 + ch],
                          __float_as_uint(m));
                atomicAdd(&poolsm[(layer * NGRAPH + g) * 64 + ch], s);
            }
        }
        __syncthreads();
    }
}

// ---------------- fused MLP head ----------------
__global__ __launch_bounds__(256) void head_kernel(
    const float* __restrict__ poolmx, const float* __restrict__ poolsm,
    const float* __restrict__ W1, const float* __restrict__ b1,
    const float* __restrict__ W2, const float* __restrict__ b2,
    const float* __restrict__ W3, const float* __restrict__ b3,
    float* __restrict__ out) {
    int g = blockIdx.x, t = threadIdx.x;
    __shared__ float repL[128], o1sh[256], o2sh[128];
    if (t < 128) {
        int d = t & 63;
        int start = (N_NODES * g + 63) >> 6;
        int end = (N_NODES * (g + 1) + 63) >> 6;
        float v = 0.f;
        if (t < 64) {
#pragma unroll
            for (int l = 0; l < NLAYER; l++) v += poolmx[(l * NGRAPH + g) * 64 + d];
        } else {
            float inv = 1.f / (float)(end - start);
#pragma unroll
            for (int l = 0; l < NLAYER; l++) v += poolsm[(l * NGRAPH + g) * 64 + d] * inv;
        }
        repL[t] = v;
    }
    __syncthreads();
    float a1 = b1[t];
    for (int k = 0; k < 128; k++) a1 += repL[k] * W1[k * 256 + t];
    o1sh[t] = fmaxf(a1, 0.f);
    __syncthreads();
    if (t < 128) {
        float a2 = b2[t];
        for (int k = 0; k < 256; k++) a2 += o1sh[k] * W2[k * 128 + t];
        o2sh[t] = fmaxf(a2, 0.f);
    }
    __syncthreads();
    if (t < 64) {
        float p = o2sh[t] * W3[t] + o2sh[t + 64] * W3[t + 64];
#pragma unroll
        for (int off = 32; off; off >>= 1) p += __shfl_xor(p, off);
        if (t == 0) out[g] = p + b3[0];
    }
}

extern "C" void kernel_launch(void* const* d_in, const int* in_sizes, int n_in,
                              void* d_out, int out_size, void* d_ws, size_t ws_size,
                              hipStream_t stream) {
    const float* x         = (const float*)d_in[0];
    const float* edge_attr = (const float*)d_in[1];
    const int*   ei        = (const int*)d_in[2];
    const float* Wq  = (const float*)d_in[4];
    const float* bq  = (const float*)d_in[5];
    const float* Wk  = (const float*)d_in[6];
    const float* bk  = (const float*)d_in[7];
    const float* Wv  = (const float*)d_in[8];
    const float* bv  = (const float*)d_in[9];
    const float* We  = (const float*)d_in[10];
    const float* Wsk = (const float*)d_in[11];
    const float* bsk = (const float*)d_in[12];
    const float* gam = (const float*)d_in[13];
    const float* bet = (const float*)d_in[14];
    const float* Wt  = (const float*)d_in[15];
    const float* bt  = (const float*)d_in[16];
    const float* W1  = (const float*)d_in[17];
    const float* b1  = (const float*)d_in[18];
    const float* W2  = (const float*)d_in[19];
    const float* b2  = (const float*)d_in[20];
    const float* W3  = (const float*)d_in[21];
    const float* b3  = (const float*)d_in[22];
    float* out = (float*)d_out;

    char* ws = (char*)d_ws;
    size_t off = 0;
    auto alloc = [&](size_t bytes) -> char* {
        char* p = ws + off;
        off += (bytes + 255) & ~(size_t)255;
        return p;
    };
    int*   rowptr = (int*)alloc((N_NODES + 1) * sizeof(int));
    int*   eidx   = (int*)alloc((size_t)N_EDGES * sizeof(int));
    int*   esrc   = (int*)alloc(((size_t)N_EDGES + 64) * sizeof(int));
    unsigned short* qbf  = (unsigned short*)alloc((size_t)N_NODES * 256 * 2);
    unsigned char*  kvf8 = (unsigned char*)alloc((size_t)N_NODES * 512);
    unsigned short* sbf  = (unsigned short*)alloc((size_t)N_NODES * 256 * 2);
    unsigned short* ubf  = (unsigned short*)alloc((size_t)N_NODES * 256 * 2);
    unsigned short* hskb = (unsigned short*)alloc((size_t)N_NODES * 256 * 2);
    unsigned short* raccb= (unsigned short*)alloc((size_t)N_NODES * 256 * 2);
    unsigned short* hbf  = (unsigned short*)alloc((size_t)N_PAD * 256 * 2);
    unsigned short* xbf  = (unsigned short*)alloc((size_t)N_PAD * 64 * 2);
    unsigned short* WallT = (unsigned short*)alloc((size_t)NLAYER * 81920 * 2);
    float* ball   = (float*)alloc((size_t)NLAYER * 1280 * sizeof(float));
    // ---- contiguous zero-init region (one memset per launch) ----
    size_t zero_off = off;
    int*   cur1   = (int*)alloc(N_NODES * sizeof(int));
    int*   cur2   = (int*)alloc(N_NODES * sizeof(int));
    float* statsA = (float*)alloc((size_t)NLAYER * 8 * 512 * sizeof(float));
    float* poolmx = (float*)alloc((size_t)NLAYER * NGRAPH * 64 * sizeof(float));
    float* poolsm = (float*)alloc((size_t)NLAYER * NGRAPH * 64 * sizeof(float));
    size_t zero_bytes = off - zero_off;
    // ---- optional permuted fp8 edge_attr ----
    unsigned char* eaP8 = (unsigned char*)alloc((size_t)N_EDGES * 64);
    bool perm = (off <= ws_size);

    hipMemsetAsync(ws + zero_off, 0, zero_bytes, stream);

    count_kernel<<<(N_EDGES + 255) / 256, 256, 0, stream>>>(ei, cur1);
    scan_kernel<<<1, 256, 0, stream>>>(cur1, rowptr);
    fill_kernel<<<(N_EDGES + 255) / 256, 256, 0, stream>>>(ei, rowptr, cur2, eidx, esrc);
    if (perm) {
        permute_ea_8_kernel<<<(N_EDGES * 8 + 255) / 256, 256, 0, stream>>>(
            edge_attr, eidx, eaP8);
    }

    wallt2_kernel<<<dim3(1280, NLAYER), 64, 0, stream>>>(
        Wq, Wk, Wv, Wsk, We, bq, bk, bv, bsk, WallT, ball);
    xtobf_kernel<<<(N_PAD * 64 / 4 + 255) / 256, 256, 0, stream>>>(x, xbf);

    for (int i = 0; i < NLAYER; i++) {
        gemm_qkvsu4_kernel<<<dim3(79, 10), 256, 0, stream>>>(
            xbf, WallT + (size_t)i * 81920, ball + i * 1280, qbf, kvf8, sbf, ubf);

        attn11_kernel<<<2500, 256, 0, stream>>>(
            perm ? eaP8 : (const unsigned char*)nullptr, edge_attr,
            eidx, rowptr, esrc, qbf, ubf, kvf8, sbf, hskb, raccb);

        msgbn2_kernel<<<1250, 256, 0, stream>>>(
            raccb, We + i * 16384, hskb, hbf, statsA + (size_t)i * 4096);

        xform5_kernel<<<157, 256, 0, stream>>>(
            hbf, Wt + i * 16384, gam + i * 256, bet + i * 256, bt + i * 64,
            statsA + (size_t)i * 4096, xbf, poolmx, poolsm, i);
    }

    head_kernel<<<64, 256, 0, stream>>>(poolmx, poolsm, W1, b1, W2, b2, W3, b3, out);
}